// Round 8
// baseline (275.505 us; speedup 1.0000x reference)
//
#include <hip/hip_runtime.h>
#include <hip/hip_bf16.h>
#include <math.h>

typedef __hip_bfloat16 bf16;
typedef __attribute__((ext_vector_type(16))) float f32x16;
typedef __attribute__((ext_vector_type(8))) short s16x8;

typedef const __attribute__((address_space(1))) void gvoid_t;
typedef __attribute__((address_space(3))) void lvoid_t;

__device__ __forceinline__ void gload16(const void* g, void* l) {
  // async global->LDS, 16B/lane; LDS dest is wave-uniform base + lane*16
  __builtin_amdgcn_global_load_lds((gvoid_t*)g, (lvoid_t*)l, 16, 0, 0);
}
__device__ __forceinline__ unsigned short f2b(float f) {
  bf16 h = __float2bfloat16(f);
  return *(unsigned short*)&h;
}
// row-dependent XOR mask for LDS chunk swizzle; distinct for rows r, r+8,
// r+16, r+24 so 32-row 32x32 frag reads alias at most 2-way (free, m136)
__device__ __forceinline__ int swz(int r) { return (r ^ (r >> 3)) & 7; }

// ---------------- prep: x = concat(patches, positions) -> bf16 [16384][832]
__global__ __launch_bounds__(256) void prep_x(const float* __restrict__ patches,
                                              const float* __restrict__ positions,
                                              bf16* __restrict__ xb) {
  const long long row = blockIdx.x;
  const int c = threadIdx.x;
  const bool lo = (c < 192);
  const bool hi = (c >= 192) && (c < 208);
  const float* src = lo ? (patches + row * 768 + c * 4)
                        : (positions + row * 64 + (c - 192) * 4);
  if (lo || hi) {
    float4 v = *(const float4*)src;
    const int dst = lo ? (c * 4) : (768 + (c - 192) * 4);
    uint2 w;
    w.x = (unsigned int)f2b(v.x) | ((unsigned int)f2b(v.y) << 16);
    w.y = (unsigned int)f2b(v.z) | ((unsigned int)f2b(v.w) << 16);
    *(uint2*)(xb + row * 832 + dst) = w;
  }
}

// ---------------- prep: Wt[z*512+n][k] = W_z[k][n] bf16 (832x512 -> 512x832)
__global__ __launch_bounds__(256) void prep_w(const float* __restrict__ Wq,
                                              const float* __restrict__ Wk,
                                              const float* __restrict__ Wv,
                                              bf16* __restrict__ Wt) {
  __shared__ float tile[32][33];
  const int z = blockIdx.z;
  const float* W = (z == 0) ? Wq : (z == 1) ? Wk : Wv;
  bf16* T = Wt + (long long)z * 512 * 832;
  const int n0 = blockIdx.x * 32;
  const int k0 = blockIdx.y * 32;
  const int tx = threadIdx.x, ty = threadIdx.y;  // (32,8)
  #pragma unroll
  for (int i = 0; i < 32; i += 8)
    tile[ty + i][tx] = W[(long long)(k0 + ty + i) * 512 + n0 + tx];
  __syncthreads();
  #pragma unroll
  for (int i = 0; i < 32; i += 8)
    T[(long long)(n0 + ty + i) * 832 + k0 + tx] = __float2bfloat16(tile[tx][ty + i]);
}

// ---------------- fused QKV projection: [16384,832] x [1536,832]^T
// 32x32x16 MFMA (half the instruction stream of 16x16x32 at a better rate).
// A/B frag: 8 contiguous k at row lane&31, k-half lane>>5.
// C/D: col=lane&31, row=(reg&3)+8*(reg>>2)+4*(lane>>5).
__global__ __launch_bounds__(256) void gemm_qkv(
    const bf16* __restrict__ xb, const bf16* __restrict__ Wt,
    const float* __restrict__ bq, const float* __restrict__ bk,
    const float* __restrict__ bv,
    bf16* __restrict__ qk, bf16* __restrict__ vt) {
  __shared__ bf16 As[128 * 64];
  __shared__ bf16 Bs[128 * 64];
  const int tid = threadIdx.x;
  const int wave = tid >> 6, lane = tid & 63;
  const int l31 = lane & 31, l5 = lane >> 5;
  const int wm = wave >> 1, wn = wave & 1;

  const unsigned int lin = blockIdx.x;        // 1536 blocks
  const unsigned int xcd = lin & 7u, idx = lin >> 3;
  const unsigned int g = xcd * 192u + idx;
  const unsigned int bm_t = g / 12u;          // 0..127
  const unsigned int bn_t = g - bm_t * 12u;   // 0..11
  const int row0 = (int)bm_t * 128;
  const int col0 = (int)bn_t * 128;
  const int z = col0 >> 9;

  f32x16 acc[2][2] = {};

  for (int kt = 0; kt < 832; kt += 64) {
    #pragma unroll
    for (int i = 0; i < 4; i++) {
      const int c = i * 256 + tid;
      const int r = c >> 3, cc = c & 7;
      const int kk = (cc ^ swz(r)) << 3;      // XOR swizzle via global addr
      gload16(xb + ((long long)(row0 + r) * 832 + kt + kk),
              (char*)As + (long long)(i * 256 + wave * 64) * 16);
      gload16(Wt + ((long long)(col0 + r) * 832 + kt + kk),
              (char*)Bs + (long long)(i * 256 + wave * 64) * 16);
    }
    __syncthreads();
    #pragma unroll
    for (int s = 0; s < 4; s++) {  // 4 k-steps of 16
      s16x8 af[2], bfr[2];
      #pragma unroll
      for (int mt = 0; mt < 2; mt++) {
        const int row = wm * 64 + mt * 32 + l31;
        af[mt] = *(const s16x8*)&As[row * 64 + (((s * 2 + l5) ^ swz(row)) << 3)];
      }
      #pragma unroll
      for (int nt = 0; nt < 2; nt++) {
        const int row = wn * 64 + nt * 32 + l31;
        bfr[nt] = *(const s16x8*)&Bs[row * 64 + (((s * 2 + l5) ^ swz(row)) << 3)];
      }
      #pragma unroll
      for (int mt = 0; mt < 2; mt++)
        #pragma unroll
        for (int nt = 0; nt < 2; nt++)
          acc[mt][nt] = __builtin_amdgcn_mfma_f32_32x32x16_bf16(
              af[mt], bfr[nt], acc[mt][nt], 0, 0, 0);
    }
    __syncthreads();
  }

  if (z < 2) {
    const float* bias = z ? bk : bq;
    bf16* outp = qk + (long long)z * 16384 * 512;
    #pragma unroll
    for (int mt = 0; mt < 2; mt++)
      #pragma unroll
      for (int nt = 0; nt < 2; nt++) {
        const int c = (col0 & 511) + wn * 64 + nt * 32 + l31;
        const float bb = bias[c];
        const int gb = row0 + wm * 64 + mt * 32 + 4 * l5;
        #pragma unroll
        for (int reg = 0; reg < 16; reg++) {
          const int grow = gb + (reg & 3) + 8 * (reg >> 2);
          outp[(long long)grow * 512 + c] =
              __float2bfloat16(acc[mt][nt][reg] + bb);
        }
      }
  } else {
    #pragma unroll
    for (int mt = 0; mt < 2; mt++)
      #pragma unroll
      for (int nt = 0; nt < 2; nt++) {
        const int c = (col0 & 511) + wn * 64 + nt * 32 + l31;
        const float bb = bv[c];
        const int gb = row0 + wm * 64 + mt * 32 + 4 * l5;
        #pragma unroll
        for (int hi = 0; hi < 4; hi++) {
          const int rr = gb + 8 * hi;       // rows rr..rr+3 = consecutive j
          const int b = rr >> 11, j = rr & 2047;
          uint2 w;
          w.x = (unsigned int)f2b(acc[mt][nt][hi * 4 + 0] + bb) |
                ((unsigned int)f2b(acc[mt][nt][hi * 4 + 1] + bb) << 16);
          w.y = (unsigned int)f2b(acc[mt][nt][hi * 4 + 2] + bb) |
                ((unsigned int)f2b(acc[mt][nt][hi * 4 + 3] + bb) << 16);
          *(uint2*)(vt + (long long)b * 512 * 2048 + (long long)c * 2048 + j) = w;
        }
      }
  }
}

// ---------------- scores+exp: P[b] = exp(Q[b] K[b]^T * alpha), bf16 out.
// Row partials -> rowsumP[8][16][2048] via plain stores (no atomics).
__global__ __launch_bounds__(256) void gemm_scores(const bf16* __restrict__ qk,
                                                   bf16* __restrict__ S,
                                                   float* __restrict__ rowsumP) {
  __shared__ bf16 As[128 * 64];
  __shared__ bf16 Bs[128 * 64];
  __shared__ float psum[4][64];
  const int tid = threadIdx.x;
  const int wave = tid >> 6, lane = tid & 63;
  const int l31 = lane & 31, l5 = lane >> 5;
  const int wm = wave >> 1, wn = wave & 1;

  const unsigned int lin = blockIdx.x;  // 2048
  const unsigned int xcd = lin & 7u, idx = lin >> 3;
  const unsigned int g = xcd * 256u + idx;
  const int b = (int)(g >> 8);
  const unsigned int rem = g & 255u;
  const int row0 = (int)(rem >> 4) * 128;
  const int coltile = (int)(rem & 15u);
  const int col0 = coltile * 128;

  const bf16* Ab = qk + (long long)b * 2048 * 512;                           // Q
  const bf16* Bb = qk + (long long)16384 * 512 + (long long)b * 2048 * 512;  // K

  f32x16 acc[2][2] = {};
  for (int kt = 0; kt < 512; kt += 64) {
    #pragma unroll
    for (int i = 0; i < 4; i++) {
      const int c = i * 256 + tid;
      const int r = c >> 3, cc = c & 7;
      const int kk = (cc ^ swz(r)) << 3;
      gload16(Ab + ((long long)(row0 + r) * 512 + kt + kk),
              (char*)As + (long long)(i * 256 + wave * 64) * 16);
      gload16(Bb + ((long long)(col0 + r) * 512 + kt + kk),
              (char*)Bs + (long long)(i * 256 + wave * 64) * 16);
    }
    __syncthreads();
    #pragma unroll
    for (int s = 0; s < 4; s++) {
      s16x8 af[2], bfr[2];
      #pragma unroll
      for (int mt = 0; mt < 2; mt++) {
        const int row = wm * 64 + mt * 32 + l31;
        af[mt] = *(const s16x8*)&As[row * 64 + (((s * 2 + l5) ^ swz(row)) << 3)];
      }
      #pragma unroll
      for (int nt = 0; nt < 2; nt++) {
        const int row = wn * 64 + nt * 32 + l31;
        bfr[nt] = *(const s16x8*)&Bs[row * 64 + (((s * 2 + l5) ^ swz(row)) << 3)];
      }
      #pragma unroll
      for (int mt = 0; mt < 2; mt++)
        #pragma unroll
        for (int nt = 0; nt < 2; nt++)
          acc[mt][nt] = __builtin_amdgcn_mfma_f32_32x32x16_bf16(
              af[mt], bfr[nt], acc[mt][nt], 0, 0, 0);
    }
    __syncthreads();
  }

  const float alpha = 0.044194173824159216f;  // 1/sqrt(512)
  #pragma unroll
  for (int mt = 0; mt < 2; mt++)
    #pragma unroll
    for (int nt = 0; nt < 2; nt++)
      #pragma unroll
      for (int reg = 0; reg < 16; reg++)
        acc[mt][nt][reg] = __expf(acc[mt][nt][reg] * alpha);

  bf16* Sb = S + (long long)b * 2048 * 2048;
  #pragma unroll
  for (int mt = 0; mt < 2; mt++)
    #pragma unroll
    for (int nt = 0; nt < 2; nt++) {
      const int gcol = col0 + wn * 64 + nt * 32 + l31;
      const int gb = row0 + wm * 64 + mt * 32 + 4 * l5;
      #pragma unroll
      for (int reg = 0; reg < 16; reg++) {
        const int grow = gb + (reg & 3) + 8 * (reg >> 2);
        Sb[(long long)grow * 2048 + gcol] = __float2bfloat16(acc[mt][nt][reg]);
      }
    }

  // row partials: sum over nt in-lane + shfl over the 32 l31 lanes,
  // cross-wave (wn) combine via LDS, plain store.
  #pragma unroll
  for (int mt = 0; mt < 2; mt++)
    #pragma unroll
    for (int reg = 0; reg < 16; reg++) {
      float p = acc[mt][0][reg] + acc[mt][1][reg];
      p += __shfl_xor(p, 1, 64);
      p += __shfl_xor(p, 2, 64);
      p += __shfl_xor(p, 4, 64);
      p += __shfl_xor(p, 8, 64);
      p += __shfl_xor(p, 16, 64);
      if (l31 == 0)
        psum[wave][mt * 32 + (reg & 3) + 8 * (reg >> 2) + 4 * l5] = p;
    }
  __syncthreads();
  if (tid < 128) {
    const int wmx = tid >> 6, i = tid & 63;
    const float v = psum[wmx * 2][i] + psum[wmx * 2 + 1][i];
    rowsumP[((long long)(b * 16 + coltile)) * 2048 + row0 + wmx * 64 + i] = v;
  }
}

// ---------------- PV: out[b] = (P[b] V[b]) / rowsum, fp32 out.
// 128x128 tiles, grid 512, one batch/XCD; rowsum reduction folded into the
// prologue (reads 16 partials/row -> rinvL in LDS), saving a dispatch.
__global__ __launch_bounds__(256) void gemm_pv(const bf16* __restrict__ S,
                                               const bf16* __restrict__ vt,
                                               const float* __restrict__ rowsumP,
                                               float* __restrict__ out) {
  __shared__ bf16 As[128 * 64];
  __shared__ bf16 Bs[128 * 64];
  __shared__ float rinvL[128];
  const int tid = threadIdx.x;
  const int wave = tid >> 6, lane = tid & 63;
  const int l31 = lane & 31, l5 = lane >> 5;
  const int wm = wave >> 1, wn = wave & 1;

  const unsigned int lin = blockIdx.x;  // 512
  const unsigned int xcd = lin & 7u, idx = lin >> 3;  // idx 0..63
  const int b = (int)xcd;
  const int row0 = (int)(idx >> 2) * 128;
  const int col0 = (int)(idx & 3u) * 128;

  if (tid < 128) {
    const float* rp = rowsumP + ((long long)b * 16) * 2048 + row0 + tid;
    float s = 0.f;
    #pragma unroll
    for (int t = 0; t < 16; t++) s += rp[t * 2048];
    rinvL[tid] = 1.0f / s;
  }

  const bf16* Ab = S + (long long)b * 2048 * 2048;
  const bf16* Bb = vt + (long long)b * 512 * 2048;

  f32x16 acc[2][2] = {};
  for (int kt = 0; kt < 2048; kt += 64) {
    #pragma unroll
    for (int i = 0; i < 4; i++) {
      const int c = i * 256 + tid;
      const int r = c >> 3, cc = c & 7;
      const int kk = (cc ^ swz(r)) << 3;
      gload16(Ab + ((long long)(row0 + r) * 2048 + kt + kk),
              (char*)As + (long long)(i * 256 + wave * 64) * 16);
      gload16(Bb + ((long long)(col0 + r) * 2048 + kt + kk),
              (char*)Bs + (long long)(i * 256 + wave * 64) * 16);
    }
    __syncthreads();
    #pragma unroll
    for (int s = 0; s < 4; s++) {
      s16x8 af[2], bfr[2];
      #pragma unroll
      for (int mt = 0; mt < 2; mt++) {
        const int row = wm * 64 + mt * 32 + l31;
        af[mt] = *(const s16x8*)&As[row * 64 + (((s * 2 + l5) ^ swz(row)) << 3)];
      }
      #pragma unroll
      for (int nt = 0; nt < 2; nt++) {
        const int row = wn * 64 + nt * 32 + l31;
        bfr[nt] = *(const s16x8*)&Bs[row * 64 + (((s * 2 + l5) ^ swz(row)) << 3)];
      }
      #pragma unroll
      for (int mt = 0; mt < 2; mt++)
        #pragma unroll
        for (int nt = 0; nt < 2; nt++)
          acc[mt][nt] = __builtin_amdgcn_mfma_f32_32x32x16_bf16(
              af[mt], bfr[nt], acc[mt][nt], 0, 0, 0);
    }
    __syncthreads();
  }

  float* Ob = out + (long long)b * 2048 * 512;
  #pragma unroll
  for (int mt = 0; mt < 2; mt++)
    #pragma unroll
    for (int nt = 0; nt < 2; nt++) {
      const int gcol = col0 + wn * 64 + nt * 32 + l31;
      const int gb = wm * 64 + mt * 32 + 4 * l5;  // row within 128-tile
      #pragma unroll
      for (int reg = 0; reg < 16; reg++) {
        const int rl = gb + (reg & 3) + 8 * (reg >> 2);
        Ob[(long long)(row0 + rl) * 512 + gcol] = acc[mt][nt][reg] * rinvL[rl];
      }
    }
}

extern "C" void kernel_launch(void* const* d_in, const int* in_sizes, int n_in,
                              void* d_out, int out_size, void* d_ws, size_t ws_size,
                              hipStream_t stream) {
  const float* patches = (const float*)d_in[0];
  const float* positions = (const float*)d_in[1];
  const float* Wq = (const float*)d_in[2];
  const float* bq = (const float*)d_in[3];
  const float* Wk = (const float*)d_in[4];
  const float* bk = (const float*)d_in[5];
  const float* Wv = (const float*)d_in[6];
  const float* bv = (const float*)d_in[7];
  float* out = (float*)d_out;

  if (ws_size < 149356544u) return;

  char* ws = (char*)d_ws;
  bf16* Wt = (bf16*)(ws);                    // 3*512*832*2   = 2,555,904
  bf16* xb = (bf16*)(ws + 2555904);          // 16384*832*2   = 27,262,976
  bf16* qk = (bf16*)(ws + 29818880);         // 2*16384*512*2 = 33,554,432 (Q,K)
  bf16* vt = (bf16*)(ws + 63373312);         // 8*512*2048*2  = 16,777,216 (V^T)
  bf16* S  = (bf16*)(ws + 80150528);         // 8*2048*2048*2 = 67,108,864
  float* rowsumP = (float*)(ws + 147259392); // 8*16*2048*4   = 2,097,152

  prep_x<<<16384, 256, 0, stream>>>(patches, positions, xb);
  prep_w<<<dim3(16, 26, 3), dim3(32, 8), 0, stream>>>(Wq, Wk, Wv, Wt);
  gemm_qkv<<<1536, 256, 0, stream>>>(xb, Wt, bq, bk, bv, qk, vt);
  gemm_scores<<<2048, 256, 0, stream>>>(qk, S, rowsumP);
  gemm_pv<<<512, 256, 0, stream>>>(S, vt, rowsumP, out);
}